// Round 1
// baseline (175.596 us; speedup 1.0000x reference)
//
#include <hip/hip_runtime.h>

#define K_KNOTS 1024
#define N_CTRL  1021
#define TABM    8192   // lookup-table buckets; K/TABM = 0.125 knots/bucket

// ---------------------------------------------------------------------------
// Kernel 1: rank sort of the 1024 knots (stable, tie-safe).
// All lanes read the same LDS address per iteration -> broadcast, conflict-free.
// ---------------------------------------------------------------------------
__global__ void sort_knots_kernel(const float* __restrict__ knots,
                                  float* __restrict__ ts) {
    __shared__ float kl[K_KNOTS];
    const int tid = threadIdx.x;
    const int gid = blockIdx.x * blockDim.x + tid;   // 0..1023 (16 blocks x 64)
    for (int i = tid; i < K_KNOTS; i += blockDim.x) kl[i] = knots[i];
    __syncthreads();
    const float my = kl[gid];
    int rank = 0;
#pragma unroll 8
    for (int j = 0; j < K_KNOTS; ++j) {
        const float v = kl[j];
        rank += (v < my || (v == my && j < gid)) ? 1 : 0;
    }
    ts[rank] = my;   // ranks form a permutation -> every slot written
}

// ---------------------------------------------------------------------------
// Kernel 2: bucket table. tab[b] = #{ ts < b/TABM - 1e-6 }  (safe lower bound
// for any x with floor(x*TABM)==b; fp error of x*TABM is < 2^-24 in x-space).
// ---------------------------------------------------------------------------
__global__ void build_table_kernel(const float* __restrict__ ts,
                                   unsigned short* __restrict__ tab) {
    __shared__ float tss[K_KNOTS];
    const int tid = threadIdx.x;
    for (int i = tid; i < K_KNOTS; i += blockDim.x) tss[i] = ts[i];
    __syncthreads();
    const int b = blockIdx.x * blockDim.x + tid;     // 0..TABM-1
    const float L = (float)b * (1.0f / (float)TABM) - 1e-6f;
    int lo = 0, hi = K_KNOTS;                        // lower_bound(ts, L)
    while (lo < hi) {
        const int mid = (lo + hi) >> 1;
        if (tss[mid] < L) lo = mid + 1; else hi = mid;
    }
    tab[b] = (unsigned short)lo;
}

// ---------------------------------------------------------------------------
// Kernel 3: de Boor evaluation.
// cnt = searchsorted_left(ts, x); k = cnt-1+p.  In the valid domain
// cnt in [4,1020], so tp (edge-padded) reduces to tp[i] = ts[i-3] and the
// control-point index (k-6+j) mod n never wraps. Accesses per point:
//   T[0..5] = ts[cnt-3 .. cnt+2],  d[0..3] = c[cnt-4 .. cnt-1].
// ---------------------------------------------------------------------------
__device__ __forceinline__ float eval_one(float x,
                                          const float* __restrict__ ts,
                                          const float* __restrict__ cs,
                                          const unsigned short* __restrict__ tab) {
    int b = (int)(x * (float)TABM);
    b = b < 0 ? 0 : (b > TABM - 1 ? TABM - 1 : b);
    int s = tab[b];
    while (s < K_KNOTS && ts[s] < x) ++s;            // expected ~1.1 iterations
    s = s < 4 ? 4 : (s > 1020 ? 1020 : s);           // domain-guaranteed; safety clamp

    const float T0 = ts[s - 3], T1 = ts[s - 2], T2 = ts[s - 1];
    const float T3 = ts[s],     T4 = ts[s + 1], T5 = ts[s + 2];
    float d0 = cs[s - 4], d1 = cs[s - 3], d2 = cs[s - 2], d3 = cs[s - 1];

    float a;
    // r = 1  (j = 3, 2, 1)
    a = (x - T2) * __builtin_amdgcn_rcpf(T5 - T2);  d3 = d2 + a * (d3 - d2);
    a = (x - T1) * __builtin_amdgcn_rcpf(T4 - T1);  d2 = d1 + a * (d2 - d1);
    a = (x - T0) * __builtin_amdgcn_rcpf(T3 - T0);  d1 = d0 + a * (d1 - d0);
    // r = 2  (j = 3, 2)
    a = (x - T2) * __builtin_amdgcn_rcpf(T4 - T2);  d3 = d2 + a * (d3 - d2);
    a = (x - T1) * __builtin_amdgcn_rcpf(T3 - T1);  d2 = d1 + a * (d2 - d1);
    // r = 3  (j = 3)
    a = (x - T2) * __builtin_amdgcn_rcpf(T3 - T2);  d3 = d2 + a * (d3 - d2);
    return d3;
}

__global__ __launch_bounds__(256) void eval_kernel(
        const float4* __restrict__ x4,
        const float* __restrict__ c,
        const float* __restrict__ ts_g,
        const unsigned short* __restrict__ tab_g,
        float4* __restrict__ out4, int n4) {
    __shared__ __align__(16) float ts_s[K_KNOTS];          // 4 KB
    __shared__ __align__(16) float cs_s[K_KNOTS];          // 4 KB (1021 used)
    __shared__ __align__(16) unsigned short tab_s[TABM];   // 16 KB
    const int tid = threadIdx.x;

    // Stage ts (256 x float4), table (1024 x uint4), c (scalar, 1021).
    ((float4*)ts_s)[tid] = ((const float4*)ts_g)[tid];
#pragma unroll
    for (int i = tid; i < TABM * 2 / 16; i += 256)
        ((uint4*)tab_s)[i] = ((const uint4*)tab_g)[i];
    for (int i = tid; i < N_CTRL; i += 256) cs_s[i] = c[i];
    __syncthreads();

    const int gid    = blockIdx.x * 256 + tid;
    const int stride = gridDim.x * 256;
    for (int i = gid; i < n4; i += stride) {
        const float4 xv = x4[i];
        float4 r;
        r.x = eval_one(xv.x, ts_s, cs_s, tab_s);
        r.y = eval_one(xv.y, ts_s, cs_s, tab_s);
        r.z = eval_one(xv.z, ts_s, cs_s, tab_s);
        r.w = eval_one(xv.w, ts_s, cs_s, tab_s);
        out4[i] = r;
    }
}

extern "C" void kernel_launch(void* const* d_in, const int* in_sizes, int n_in,
                              void* d_out, int out_size, void* d_ws, size_t ws_size,
                              hipStream_t stream) {
    const float* x     = (const float*)d_in[0];  // [16777216]
    const float* knots = (const float*)d_in[1];  // [1024] unsorted
    const float* c     = (const float*)d_in[2];  // [1021]
    float* out = (float*)d_out;

    float* ts_ws = (float*)d_ws;                                    // 4 KB
    unsigned short* tab_ws =
        (unsigned short*)((char*)d_ws + K_KNOTS * sizeof(float));   // 16 KB, 16B-aligned

    sort_knots_kernel<<<16, 64, 0, stream>>>(knots, ts_ws);
    build_table_kernel<<<TABM / 256, 256, 0, stream>>>(ts_ws, tab_ws);

    const int n4 = out_size / 4;   // 4,194,304
    eval_kernel<<<2048, 256, 0, stream>>>((const float4*)x, c, ts_ws, tab_ws,
                                          (float4*)out, n4);
}

// Round 2
// 160.321 us; speedup vs baseline: 1.0953x; 1.0953x over previous
//
#include <hip/hip_runtime.h>

#define K_KNOTS 1024
#define N_CTRL  1021
#define TABM    4096   // lookup-table buckets; 0.25 knots/bucket avg

// ---------------------------------------------------------------------------
// Kernel 1: rank sort of the 1024 knots (stable, tie-safe).
// float4 LDS reads: 256 b128 broadcasts instead of 1024 b32 (latency amortized,
// the 16 blocks each hold 1 wave so there's no TLP to hide ds_read latency).
// ---------------------------------------------------------------------------
__global__ void sort_knots_kernel(const float* __restrict__ knots,
                                  float* __restrict__ ts) {
    __shared__ __align__(16) float kl[K_KNOTS];
    const int tid = threadIdx.x;
    const int gid = blockIdx.x * blockDim.x + tid;   // 0..1023 (16 blocks x 64)
    for (int i = tid; i < K_KNOTS / 4; i += blockDim.x)
        ((float4*)kl)[i] = ((const float4*)knots)[i];
    __syncthreads();
    const float my = kl[gid];
    int rank = 0;
    const float4* kl4 = (const float4*)kl;
#pragma unroll 8
    for (int j4 = 0; j4 < K_KNOTS / 4; ++j4) {
        const float4 v = kl4[j4];
        const int j = j4 * 4;
        rank += (v.x < my || (v.x == my && j + 0 < gid)) ? 1 : 0;
        rank += (v.y < my || (v.y == my && j + 1 < gid)) ? 1 : 0;
        rank += (v.z < my || (v.z == my && j + 2 < gid)) ? 1 : 0;
        rank += (v.w < my || (v.w == my && j + 3 < gid)) ? 1 : 0;
    }
    ts[rank] = my;   // ranks form a permutation -> every slot written
}

// ---------------------------------------------------------------------------
// Kernel 2 (fused prep): blocks 0..15 build the bucket table,
// blocks 16..19 build per-interval cubic coefficients in u = x - ts[s].
//
// For count s (ts[s-1] < x <= ts[s]), de Boor reduces to a cubic in x with
// knots T0..T5 = ts[s-3..s+2] and d0..d3 = c[s-4..s-1] (valid domain keeps
// s in [4,1020] so the edge-pad / negative-wrap never trigger).
// alpha(x) = (x-tl)/(tr-tl) = A + inv*u with A=(tref-tl)*inv -> lerp in
// coefficient space keeps everything degree<=3.
// ---------------------------------------------------------------------------
struct Poly { float c0, c1, c2, c3; };

__device__ __forceinline__ Poly lerp_poly(const Poly dl, const Poly dr,
                                          float tl, float tr, float tref) {
    const float inv = 1.0f / (tr - tl);
    const float A = (tref - tl) * inv;
    const float e0 = dr.c0 - dl.c0, e1 = dr.c1 - dl.c1;
    const float e2 = dr.c2 - dl.c2, e3 = dr.c3 - dl.c3;
    Poly o;
    o.c0 = dl.c0 + A * e0;
    o.c1 = dl.c1 + A * e1 + inv * e0;   // u*e shifts coeffs up one degree
    o.c2 = dl.c2 + A * e2 + inv * e1;
    o.c3 = dl.c3 + A * e3 + inv * e2;   // e3==0 until the last level
    return o;
}

__global__ void prep_kernel(const float* __restrict__ ts,
                            const float* __restrict__ c,
                            unsigned short* __restrict__ tab,
                            float4* __restrict__ coef) {
    __shared__ float tss[K_KNOTS];
    const int tid = threadIdx.x;
    for (int i = tid; i < K_KNOTS; i += blockDim.x) tss[i] = ts[i];
    __syncthreads();

    if (blockIdx.x < TABM / 256) {
        // tab[b] = #{ ts < b/TABM - 1e-6 }: safe lower bound for any x with
        // (int)(x*TABM)==b (fp rounding of x*TABM is < 6e-8 in x-space).
        const int b = blockIdx.x * 256 + tid;
        const float L = (float)b * (1.0f / (float)TABM) - 1e-6f;
        int lo = 0, hi = K_KNOTS;
        while (lo < hi) {
            const int mid = (lo + hi) >> 1;
            if (tss[mid] < L) lo = mid + 1; else hi = mid;
        }
        tab[b] = (unsigned short)lo;
    } else {
        const int s = (blockIdx.x - TABM / 256) * 256 + tid;   // 0..1023
        float4 out = make_float4(0.f, 0.f, 0.f, 0.f);
        if (s >= 4 && s <= 1020) {
            const float T0 = tss[s - 3], T1 = tss[s - 2], T2 = tss[s - 1];
            const float T3 = tss[s],     T4 = tss[s + 1], T5 = tss[s + 2];
            const float tref = T3;
            Poly d0 = {c[s - 4], 0, 0, 0}, d1 = {c[s - 3], 0, 0, 0};
            Poly d2 = {c[s - 2], 0, 0, 0}, d3 = {c[s - 1], 0, 0, 0};
            d3 = lerp_poly(d2, d3, T2, T5, tref);   // r=1
            d2 = lerp_poly(d1, d2, T1, T4, tref);
            d1 = lerp_poly(d0, d1, T0, T3, tref);
            d3 = lerp_poly(d2, d3, T2, T4, tref);   // r=2
            d2 = lerp_poly(d1, d2, T1, T3, tref);
            d3 = lerp_poly(d2, d3, T2, T3, tref);   // r=3
            out = make_float4(d3.c0, d3.c1, d3.c2, d3.c3);
        }
        coef[s] = out;
    }
}

// ---------------------------------------------------------------------------
// Kernel 3: evaluation. Per point: 1 u16 tab read, ~1-2 b32 scan reads
// (scan-exit value == ts[s] == tref, so the recenter point is free),
// 1 aligned ds_read_b128 coef gather, Horner (3 FMA).
// ---------------------------------------------------------------------------
__device__ __forceinline__ float eval_one(float x,
                                          const float* __restrict__ ts,
                                          const float4* __restrict__ coef,
                                          const unsigned short* __restrict__ tab) {
    int b = (int)(x * (float)TABM);
    b = b < 0 ? 0 : (b > TABM - 1 ? TABM - 1 : b);
    int s = tab[b];
    float t = ts[s];
    while (t < x) { ++s; t = ts[s]; }   // expected ~1.1 scalar iterations
    const float u = x - t;              // t == ts[s] == tref, u <= 0
    const float4 cf = coef[s];
    return cf.x + u * (cf.y + u * (cf.z + u * cf.w));
}

__global__ __launch_bounds__(256) void eval_kernel(
        const float4* __restrict__ x4,
        const float* __restrict__ ts_g,
        const float4* __restrict__ coef_g,
        const unsigned short* __restrict__ tab_g,
        float4* __restrict__ out4, int n4) {
    __shared__ __align__(16) float ts_s[K_KNOTS];          // 4 KB
    __shared__ __align__(16) float4 coef_s[K_KNOTS];       // 16 KB
    __shared__ __align__(16) unsigned short tab_s[TABM];   // 8 KB  -> 28 KB total
    const int tid = threadIdx.x;

    ((float4*)ts_s)[tid] = ((const float4*)ts_g)[tid];     // 256 x 16B = 4 KB
#pragma unroll
    for (int i = tid; i < K_KNOTS; i += 256) coef_s[i] = coef_g[i];
#pragma unroll
    for (int i = tid; i < TABM * 2 / 16; i += 256)
        ((uint4*)tab_s)[i] = ((const uint4*)tab_g)[i];
    __syncthreads();

    const int gid    = blockIdx.x * 256 + tid;
    const int stride = gridDim.x * 256;
    for (int i = gid; i < n4; i += stride) {
        const float4 xv = x4[i];
        float4 r;
        r.x = eval_one(xv.x, ts_s, coef_s, tab_s);
        r.y = eval_one(xv.y, ts_s, coef_s, tab_s);
        r.z = eval_one(xv.z, ts_s, coef_s, tab_s);
        r.w = eval_one(xv.w, ts_s, coef_s, tab_s);
        out4[i] = r;
    }
}

extern "C" void kernel_launch(void* const* d_in, const int* in_sizes, int n_in,
                              void* d_out, int out_size, void* d_ws, size_t ws_size,
                              hipStream_t stream) {
    const float* x     = (const float*)d_in[0];  // [16777216]
    const float* knots = (const float*)d_in[1];  // [1024] unsorted
    const float* c     = (const float*)d_in[2];  // [1021]
    float* out = (float*)d_out;

    // ws layout: ts @0 (4 KB) | coef @4K (16 KB, 16B-aligned) | tab @20K (8 KB)
    float*  ts_ws   = (float*)d_ws;
    float4* coef_ws = (float4*)((char*)d_ws + 4096);
    unsigned short* tab_ws = (unsigned short*)((char*)d_ws + 4096 + 16384);

    sort_knots_kernel<<<16, 64, 0, stream>>>(knots, ts_ws);
    prep_kernel<<<TABM / 256 + K_KNOTS / 256, 256, 0, stream>>>(ts_ws, c, tab_ws, coef_ws);

    const int n4 = out_size / 4;   // 4,194,304
    eval_kernel<<<2048, 256, 0, stream>>>((const float4*)x, ts_ws, coef_ws, tab_ws,
                                          (float4*)out, n4);
}